// Round 1
// baseline (1254.973 us; speedup 1.0000x reference)
//
#include <hip/hip_runtime.h>
#include <math.h>

#define NN 50000
#define EE 800000
#define HD 128

__device__ __forceinline__ float bf2f(unsigned int h16) {
  union { unsigned int u; float f; } z; z.u = h16 << 16; return z.f;
}
__device__ __forceinline__ unsigned short f2bf(float f) {
  union { float f; unsigned int u; } z; z.f = f;
  return (unsigned short)((z.u + 0x7fffu + ((z.u >> 16) & 1u)) >> 16);
}
__device__ __forceinline__ float sigm(float v) { return 1.0f / (1.0f + __expf(-v)); }

// ---------------- K1: P = x @ [W1_dst | W1_src]  (50000 x 256) ----------------
__global__ __launch_bounds__(256) void k1_node_pre(const float* __restrict__ x,
                                                   const float* __restrict__ W1,
                                                   float* __restrict__ P) {
  __shared__ float As[16][132];
  __shared__ float Bs[32][260];
  const int t = threadIdx.x;
  const int n0 = blockIdx.x * 16;   // 3125 * 16 = 50000 exact

  for (int i = t; i < 16 * 32; i += 256) {
    int r = i >> 5, c4 = (i & 31) << 2;
    *(float4*)&As[r][c4] = *(const float4*)(x + (n0 + r) * HD + c4);
  }

  const int n_loc = t >> 4;
  const int c0 = (t & 15) << 2;     // cols c0 + 64*j + i
  float acc[16];
#pragma unroll
  for (int i = 0; i < 16; ++i) acc[i] = 0.0f;

  for (int k0 = 0; k0 < 128; k0 += 32) {
    __syncthreads();
    for (int i = t; i < 32 * 64; i += 256) {
      int kk = i >> 6, cc = (i & 63) << 2;
      const float* sp = (cc < 128) ? (W1 + (k0 + kk) * HD + cc)
                                   : (W1 + (128 + k0 + kk) * HD + (cc - 128));
      *(float4*)&Bs[kk][cc] = *(const float4*)sp;
    }
    __syncthreads();
#pragma unroll
    for (int k = 0; k < 32; ++k) {
      float a = As[n_loc][k0 + k];
#pragma unroll
      for (int j = 0; j < 4; ++j) {
        float4 b = *(const float4*)&Bs[k][c0 + 64 * j];
        acc[4 * j + 0] = fmaf(a, b.x, acc[4 * j + 0]);
        acc[4 * j + 1] = fmaf(a, b.y, acc[4 * j + 1]);
        acc[4 * j + 2] = fmaf(a, b.z, acc[4 * j + 2]);
        acc[4 * j + 3] = fmaf(a, b.w, acc[4 * j + 3]);
      }
    }
  }
  float* outp = P + (size_t)(n0 + n_loc) * 256;
#pragma unroll
  for (int j = 0; j < 4; ++j)
    *(float4*)(outp + c0 + 64 * j) =
        make_float4(acc[4 * j], acc[4 * j + 1], acc[4 * j + 2], acc[4 * j + 3]);
}

// ---------------- K2: fused edge kernel ----------------
// per 64-edge tile: pre = P[dst] + P[src|src-half] + b1 + ea@W1c + geom@W1g
// -> LN -> SiLU -> h ; msg = h@W2 + b2 ; atomic scatter into sums/cnt
__global__ __launch_bounds__(256) void k2_edge(const float* __restrict__ P,
                                               const float* __restrict__ edge_attr,
                                               const float* __restrict__ pos,
                                               const int* __restrict__ ei,
                                               const float* __restrict__ W1,
                                               const float* __restrict__ b1,
                                               const float* __restrict__ ln1g,
                                               const float* __restrict__ ln1b,
                                               const float* __restrict__ W2,
                                               const float* __restrict__ b2,
                                               float* __restrict__ sums,
                                               float* __restrict__ cnt) {
  __shared__ float hsh[64][132];
  __shared__ float Bs[32][132];
  __shared__ float W1c[20][132];
  __shared__ float b1s[128], g1s[128], bb1s[128], b2s[128];
  __shared__ int dsts[64], srcs[64];
  __shared__ float relv[64][4];

  const int t = threadIdx.x;
  const int e0 = blockIdx.x * 64;   // 12500 * 64 = 800000 exact

  for (int i = t; i < 20 * 128; i += 256) {
    int r = i >> 7, c = i & 127;
    W1c[r][c] = W1[(256 + r) * HD + c];
  }
  if (t < 128) { b1s[t] = b1[t]; g1s[t] = ln1g[t]; bb1s[t] = ln1b[t]; b2s[t] = b2[t]; }
  if (t < 64) {
    int e = e0 + t;
    int s = ei[e], d = ei[EE + e];
    srcs[t] = s; dsts[t] = d;
    float rx = (pos[3 * s + 0] - pos[3 * d + 0]) * 0.2f;
    float ry = (pos[3 * s + 1] - pos[3 * d + 1]) * 0.2f;
    float rz = (pos[3 * s + 2] - pos[3 * d + 2]) * 0.2f;
    relv[t][0] = rx; relv[t][1] = ry; relv[t][2] = rz;
    relv[t][3] = rx * rx + ry * ry + rz * rz;
  }
  __syncthreads();

  // ---- phase A: pre + LN + SiLU (4 threads per edge, 32 cols each) ----
  {
    const int el = t >> 2;          // 0..63
    const int cg = t & 3;           // col group: cols cg*32 .. cg*32+31
    const int e = e0 + el;
    const int s = srcs[el], d = dsts[el];
    const float* Pd = P + (size_t)d * 256 + cg * 32;
    const float* Ps = P + (size_t)s * 256 + 128 + cg * 32;
    float pre[32];
#pragma unroll
    for (int j = 0; j < 8; ++j) {
      float4 a = *(const float4*)(Pd + 4 * j);
      float4 b = *(const float4*)(Ps + 4 * j);
      pre[4 * j + 0] = a.x + b.x;
      pre[4 * j + 1] = a.y + b.y;
      pre[4 * j + 2] = a.z + b.z;
      pre[4 * j + 3] = a.w + b.w;
    }
#pragma unroll
    for (int j = 0; j < 32; ++j) pre[j] += b1s[cg * 32 + j];

    // edge_attr part, row-rotated by cg to avoid LDS bank conflicts
    float ea[16];
#pragma unroll
    for (int jj = 0; jj < 16; ++jj) ea[jj] = edge_attr[(size_t)e * 16 + ((jj + cg) & 15)];
#pragma unroll
    for (int jj = 0; jj < 16; ++jj) {
      const int jr = (jj + cg) & 15;
      const float a = ea[jj];
#pragma unroll
      for (int j = 0; j < 8; ++j) {
        float4 b = *(const float4*)&W1c[jr][cg * 32 + 4 * j];
        pre[4 * j + 0] = fmaf(a, b.x, pre[4 * j + 0]);
        pre[4 * j + 1] = fmaf(a, b.y, pre[4 * j + 1]);
        pre[4 * j + 2] = fmaf(a, b.z, pre[4 * j + 2]);
        pre[4 * j + 3] = fmaf(a, b.w, pre[4 * j + 3]);
      }
    }
    // geometric part (rows 16..19 of W1c = W1 rows 272..275)
    float rv[4];
#pragma unroll
    for (int rr = 0; rr < 4; ++rr) rv[rr] = relv[el][(rr + cg) & 3];
#pragma unroll
    for (int rr = 0; rr < 4; ++rr) {
      const int jr = (rr + cg) & 3;
      const float a = rv[rr];
#pragma unroll
      for (int j = 0; j < 8; ++j) {
        float4 b = *(const float4*)&W1c[16 + jr][cg * 32 + 4 * j];
        pre[4 * j + 0] = fmaf(a, b.x, pre[4 * j + 0]);
        pre[4 * j + 1] = fmaf(a, b.y, pre[4 * j + 1]);
        pre[4 * j + 2] = fmaf(a, b.z, pre[4 * j + 2]);
        pre[4 * j + 3] = fmaf(a, b.w, pre[4 * j + 3]);
      }
    }
    // LayerNorm over 128 (reduce across the 4 lanes of this edge)
    float s1 = 0.0f, s2 = 0.0f;
#pragma unroll
    for (int j = 0; j < 32; ++j) { s1 += pre[j]; s2 += pre[j] * pre[j]; }
    s1 += __shfl_xor(s1, 1); s2 += __shfl_xor(s2, 1);
    s1 += __shfl_xor(s1, 2); s2 += __shfl_xor(s2, 2);
    const float m = s1 * (1.0f / 128.0f);
    const float var = s2 * (1.0f / 128.0f) - m * m;
    const float rstd = rsqrtf(var + 1e-5f);
#pragma unroll
    for (int j = 0; j < 32; ++j) {
      const int c = cg * 32 + j;
      float y = g1s[c] * ((pre[j] - m) * rstd) + bb1s[c];
      pre[j] = y / (1.0f + __expf(-y));   // SiLU
    }
#pragma unroll
    for (int j = 0; j < 8; ++j)
      *(float4*)&hsh[el][cg * 32 + 4 * j] =
          make_float4(pre[4 * j], pre[4 * j + 1], pre[4 * j + 2], pre[4 * j + 3]);
  }

  // ---- phase B: msg = h @ W2 (64x128 tile, K=128), register-tiled ----
  const int eg = t >> 5;            // 0..7 -> edges eg*8 .. eg*8+7
  const int ng = t & 31;            // cols ng + 32*jn
  float acc[8][4];
#pragma unroll
  for (int i = 0; i < 8; ++i)
#pragma unroll
    for (int j = 0; j < 4; ++j) acc[i][j] = 0.0f;

  for (int kc = 0; kc < 128; kc += 32) {
    __syncthreads();
    for (int i = t; i < 32 * 32; i += 256) {
      int kk = i >> 5, c4 = (i & 31) << 2;
      *(float4*)&Bs[kk][c4] = *(const float4*)(W2 + (kc + kk) * HD + c4);
    }
    __syncthreads();
#pragma unroll
    for (int k4 = 0; k4 < 8; ++k4) {
      float4 av[8];
#pragma unroll
      for (int i = 0; i < 8; ++i)
        av[i] = *(const float4*)&hsh[eg * 8 + i][kc + k4 * 4];
#pragma unroll
      for (int kk = 0; kk < 4; ++kk) {
        float bv0 = Bs[k4 * 4 + kk][ng];
        float bv1 = Bs[k4 * 4 + kk][ng + 32];
        float bv2 = Bs[k4 * 4 + kk][ng + 64];
        float bv3 = Bs[k4 * 4 + kk][ng + 96];
#pragma unroll
        for (int i = 0; i < 8; ++i) {
          const float a = ((const float*)&av[i])[kk];
          acc[i][0] = fmaf(a, bv0, acc[i][0]);
          acc[i][1] = fmaf(a, bv1, acc[i][1]);
          acc[i][2] = fmaf(a, bv2, acc[i][2]);
          acc[i][3] = fmaf(a, bv3, acc[i][3]);
        }
      }
    }
  }

  // ---- phase C: atomic scatter-add (mean denominator via cnt) ----
#pragma unroll
  for (int i = 0; i < 8; ++i) {
    const int d = dsts[eg * 8 + i];
    float* sp = sums + (size_t)d * HD;
#pragma unroll
    for (int jn = 0; jn < 4; ++jn) {
      const int c = ng + 32 * jn;
      atomicAdd(sp + c, acc[i][jn] + b2s[c]);
    }
  }
  if (t < 64) atomicAdd(cnt + dsts[t], 1.0f);
}

// ---------------- K3: GRU + LN2, fused ----------------
// S = agg@Wih^T + x@Whh^T + bih + bhh (384 cols); ghn = (x@Whh^T + bhh)[n-gate]
__global__ __launch_bounds__(256) void k3_gru(const float* __restrict__ x,
                                              const float* __restrict__ sums,
                                              const float* __restrict__ cnt,
                                              const float* __restrict__ Wih,
                                              const float* __restrict__ bih,
                                              const float* __restrict__ Whh,
                                              const float* __restrict__ bhh,
                                              const float* __restrict__ ln2g,
                                              const float* __restrict__ ln2b,
                                              float* __restrict__ out) {
  __shared__ unsigned short As[2][32][132];   // [0]=agg, [1]=x (bf16)
  __shared__ float Bs[64][68];
  __shared__ unsigned short Ss[32][388];      // S (bf16)
  __shared__ unsigned short Gs[32][132];      // ghn (bf16)

  const int t = threadIdx.x;
  const int n0 = blockIdx.x * 32;

  for (int i = t; i < 32 * 32; i += 256) {
    int r = i >> 5, c4 = (i & 31) << 2;
    int gn = n0 + r;
    float4 va = make_float4(0, 0, 0, 0), vx = va;
    if (gn < NN) {
      va = *(const float4*)(sums + (size_t)gn * HD + c4);
      float inv = 1.0f / fmaxf(cnt[gn], 1.0f);
      va.x *= inv; va.y *= inv; va.z *= inv; va.w *= inv;
      vx = *(const float4*)(x + (size_t)gn * HD + c4);
    }
    As[0][r][c4 + 0] = f2bf(va.x); As[0][r][c4 + 1] = f2bf(va.y);
    As[0][r][c4 + 2] = f2bf(va.z); As[0][r][c4 + 3] = f2bf(va.w);
    As[1][r][c4 + 0] = f2bf(vx.x); As[1][r][c4 + 1] = f2bf(vx.y);
    As[1][r][c4 + 2] = f2bf(vx.z); As[1][r][c4 + 3] = f2bf(vx.w);
  }

  const int nl = t & 15;            // nodes 2*nl, 2*nl+1
  const int cg = t >> 4;            // cols cg*4 + j within 64-col chunk

  for (int cc = 0; cc < 6; ++cc) {
    float acc1[2][4], acc2[2][4];
#pragma unroll
    for (int p = 0; p < 2; ++p)
#pragma unroll
      for (int j = 0; j < 4; ++j) { acc1[p][j] = 0.0f; acc2[p][j] = 0.0f; }

#pragma unroll
    for (int mat = 0; mat < 2; ++mat) {
      const float* W = mat ? Whh : Wih;
      for (int kh = 0; kh < 2; ++kh) {
        __syncthreads();
        for (int i = t; i < 64 * 16; i += 256) {
          int cl = i >> 4, k4 = (i & 15) << 2;
          *(float4*)&Bs[cl][k4] =
              *(const float4*)(W + (size_t)(cc * 64 + cl) * HD + kh * 64 + k4);
        }
        __syncthreads();
#pragma unroll
        for (int k4 = 0; k4 < 16; ++k4) {
          float av[2][4];
#pragma unroll
          for (int p = 0; p < 2; ++p) {
            const uint2 u = *(const uint2*)&As[mat][2 * nl + p][kh * 64 + k4 * 4];
            av[p][0] = bf2f(u.x & 0xffffu);
            av[p][1] = bf2f(u.x >> 16);
            av[p][2] = bf2f(u.y & 0xffffu);
            av[p][3] = bf2f(u.y >> 16);
          }
#pragma unroll
          for (int j = 0; j < 4; ++j) {
            const float4 b = *(const float4*)&Bs[cg * 4 + j][k4 * 4];
#pragma unroll
            for (int p = 0; p < 2; ++p) {
              float s = fmaf(av[p][0], b.x,
                        fmaf(av[p][1], b.y,
                        fmaf(av[p][2], b.z, av[p][3] * b.w)));
              if (mat == 0) acc1[p][j] += s; else acc2[p][j] += s;
            }
          }
        }
      }
    }
#pragma unroll
    for (int j = 0; j < 4; ++j) {
      const int c = cc * 64 + cg * 4 + j;
      const float bsum = bih[c] + bhh[c];
#pragma unroll
      for (int p = 0; p < 2; ++p) {
        Ss[2 * nl + p][c] = f2bf(acc1[p][j] + acc2[p][j] + bsum);
        if (c >= 256) Gs[2 * nl + p][c - 256] = f2bf(acc2[p][j] + bhh[c]);
      }
    }
  }
  __syncthreads();

  // gates + residual + LN2
  const int g = t >> 4;             // nodes 2g, 2g+1
  const int q0 = (t & 15) << 3;     // 8 cols per thread
#pragma unroll
  for (int p = 0; p < 2; ++p) {
    const int n = 2 * g + p;
    const int gn = n0 + n;
    if (gn < NN) {
      float xv[8], vb[8];
      *(float4*)&xv[0] = *(const float4*)(x + (size_t)gn * HD + q0);
      *(float4*)&xv[4] = *(const float4*)(x + (size_t)gn * HD + q0 + 4);
      float s1 = 0.0f, s2 = 0.0f;
#pragma unroll
      for (int j = 0; j < 8; ++j) {
        const int q = q0 + j;
        float rr = sigm(bf2f(Ss[n][q]));
        float zz = sigm(bf2f(Ss[n][q + 128]));
        float gh = bf2f(Gs[n][q]);
        float nv = tanhf(bf2f(Ss[n][q + 256]) + (rr - 1.0f) * gh);
        float upd = (1.0f - zz) * nv + zz * xv[j];
        float v = xv[j] + upd;
        vb[j] = v; s1 += v; s2 += v * v;
      }
      s1 += __shfl_xor(s1, 1); s2 += __shfl_xor(s2, 1);
      s1 += __shfl_xor(s1, 2); s2 += __shfl_xor(s2, 2);
      s1 += __shfl_xor(s1, 4); s2 += __shfl_xor(s2, 4);
      s1 += __shfl_xor(s1, 8); s2 += __shfl_xor(s2, 8);
      const float m = s1 * (1.0f / 128.0f);
      const float var = s2 * (1.0f / 128.0f) - m * m;
      const float rstd = rsqrtf(var + 1e-5f);
      float ov[8];
#pragma unroll
      for (int j = 0; j < 8; ++j)
        ov[j] = ln2g[q0 + j] * ((vb[j] - m) * rstd) + ln2b[q0 + j];
      *(float4*)(out + (size_t)gn * HD + q0) = make_float4(ov[0], ov[1], ov[2], ov[3]);
      *(float4*)(out + (size_t)gn * HD + q0 + 4) = make_float4(ov[4], ov[5], ov[6], ov[7]);
    }
  }
}

extern "C" void kernel_launch(void* const* d_in, const int* in_sizes, int n_in,
                              void* d_out, int out_size, void* d_ws, size_t ws_size,
                              hipStream_t stream) {
  const float* x         = (const float*)d_in[0];
  const float* edge_attr = (const float*)d_in[1];
  const float* pos       = (const float*)d_in[2];
  const float* W1        = (const float*)d_in[3];
  const float* b1        = (const float*)d_in[4];
  const float* ln1g      = (const float*)d_in[5];
  const float* ln1b      = (const float*)d_in[6];
  const float* W2        = (const float*)d_in[7];
  const float* b2        = (const float*)d_in[8];
  const float* Wih       = (const float*)d_in[9];
  const float* bih       = (const float*)d_in[10];
  const float* Whh       = (const float*)d_in[11];
  const float* bhh       = (const float*)d_in[12];
  const float* ln2g      = (const float*)d_in[13];
  const float* ln2b      = (const float*)d_in[14];
  const int*   ei        = (const int*)d_in[15];
  float* out = (float*)d_out;

  float* P    = (float*)d_ws;                       // [NN][256]
  float* sums = P + (size_t)NN * 256;               // [NN][128]
  float* cnt  = sums + (size_t)NN * HD;             // [NN]

  hipMemsetAsync(sums, 0, (size_t)(NN * HD + NN) * sizeof(float), stream);
  k1_node_pre<<<3125, 256, 0, stream>>>(x, W1, P);
  k2_edge<<<12500, 256, 0, stream>>>(P, edge_attr, pos, ei, W1, b1, ln1g, ln1b,
                                     W2, b2, sums, cnt);
  k3_gru<<<1563, 256, 0, stream>>>(x, sums, cnt, Wih, bih, Whh, bhh,
                                   ln2g, ln2b, out);
}